// Round 1
// baseline (831.928 us; speedup 1.0000x reference)
//
#include <hip/hip_runtime.h>
#include <stdint.h>

// HiPPO-LegT scan  ->  causal convolution  c_t = sum_k f_{t-k} * (A^k B)
// Stage 1: V[k] = A^k B via A^16 jumps (fp32).  Stage 2: big f16 MFMA matmul
// C_bd = Toeplitz(f_bd) @ V  with causality baked into zero-padded reversed f.

typedef _Float16 half8 __attribute__((ext_vector_type(8)));
typedef float floatx4 __attribute__((ext_vector_type(4)));

// ---------------- prep kernels (all fp32) ----------------

__global__ void k_at(const float* __restrict__ A, float* __restrict__ At) {
    int i = blockIdx.x, j = threadIdx.x;
    At[j * 256 + i] = A[i * 256 + j];
}

// C = M @ M ; optionally also write C^T
__global__ void k_sq(const float* __restrict__ M, float* __restrict__ C,
                     float* __restrict__ Ct, int wt) {
    __shared__ float row[256];
    int i = blockIdx.x, j = threadIdx.x;
    row[j] = M[i * 256 + j];
    __syncthreads();
    float acc = 0.f;
#pragma unroll 8
    for (int k = 0; k < 256; ++k) acc += row[k] * M[k * 256 + j];
    C[i * 256 + j] = acc;
    if (wt) Ct[j * 256 + i] = acc;
}

// u_j = (A^16)^j B, j=0..31 ; U[j] = u_j ; Vt[:,16j] = u_j (fp16)
__global__ void k_u(const float* __restrict__ Bvec, const float* __restrict__ A16t,
                    float* __restrict__ U, _Float16* __restrict__ Vt) {
    __shared__ float u[256];
    int n = threadIdx.x;
    u[n] = Bvec[n];
    __syncthreads();
    for (int j = 0; j < 32; ++j) {
        U[j * 256 + n] = u[n];
        Vt[n * 512 + 16 * j] = (_Float16)u[n];
        if (j < 31) {
            float acc = 0.f;
#pragma unroll 8
            for (int m = 0; m < 256; ++m) acc += A16t[m * 256 + n] * u[m];
            __syncthreads();
            u[n] = acc;
            __syncthreads();
        }
    }
}

// block bj: v = U[bj]; 15x  v = A v ; Vt[:,16bj+i] = v
__global__ void k_v(const float* __restrict__ U, const float* __restrict__ At,
                    _Float16* __restrict__ Vt) {
    __shared__ float v[256];
    int n = threadIdx.x, bj = blockIdx.x;
    v[n] = U[bj * 256 + n];
    __syncthreads();
    for (int i = 1; i < 16; ++i) {
        float acc = 0.f;
#pragma unroll 8
        for (int m = 0; m < 256; ++m) acc += At[m * 256 + n] * v[m];
        __syncthreads();
        v[n] = acc;
        __syncthreads();
        Vt[n * 512 + 16 * bj + i] = (_Float16)acc;
    }
}

// g8[bd][r][i] = g[i+r] where g[x] = f[511-x] for x<=511 else 0 (fp16)
// 8 shifted copies so any lane's 8-contiguous-element window is 16B-aligned.
__global__ void k_g8(const float* __restrict__ inp, _Float16* __restrict__ g8) {
    int bd = blockIdx.x;
    const float* f = inp + (size_t)bd * 512;
    _Float16* g = g8 + (size_t)bd * 5248;
    for (int idx = threadIdx.x; idx < 5248; idx += 256) {
        int r = idx / 656;
        int i = idx - r * 656;
        int jj = i + r;
        float val = (jj < 512) ? f[511 - jj] : 0.f;
        g[idx] = (_Float16)val;
    }
}

// ---------------- main MFMA kernel ----------------
// block: 128(t) x 256(n), 4 waves of 64x128, K-step 32, mfma_f32_16x16x32_f16
__global__ __launch_bounds__(256, 2) void k_main(
    const _Float16* __restrict__ g8,
    const _Float16* __restrict__ Vt,
    float* __restrict__ out)
{
    __shared__ _Float16 ldsA[8 * 656];    // 10496 B: 8 shifted copies of rev-f
    __shared__ _Float16 ldsB[256 * 40];   // 20480 B: 256 n-rows, 32 k + pad

    const int tid  = threadIdx.x;
    const int lane = tid & 63;
    const int w    = tid >> 6;
    const int bd   = blockIdx.x & 1023;
    const int tt   = blockIdx.x >> 10;    // 0..3
    const int t0   = 384 - 128 * tt;      // heavy blocks first
    const int Kmax = t0 + 128;

    // stage A copies (once per block)
    {
        const uint4* gsrc = reinterpret_cast<const uint4*>(g8 + (size_t)bd * 5248);
        uint4* adst = reinterpret_cast<uint4*>(ldsA);
        for (int idx = tid; idx < 656; idx += 256) adst[idx] = gsrc[idx];
    }

    const int wave_mt = (w & 1) << 6;     // 0 / 64
    const int wave_nn = (w >> 1) << 7;    // 0 / 128
    const int m16  = lane & 15;
    const int quad = lane >> 4;
    const int hi8  = quad << 3;

    // A-frag byte offsets (k0 added in loop): i0 = k0 + hi8 + (511 - t)
    int abase[4];
#pragma unroll
    for (int mf = 0; mf < 4; ++mf) {
        int t_lane = t0 + wave_mt + mf * 16 + m16;
        int c = 511 - t_lane;
        int r = (c + hi8) & 7;            // k0 % 32 == 0 keeps r constant
        abase[mf] = r * 1312 + 2 * (hi8 + c - r);
    }
    int bbase[8];
#pragma unroll
    for (int bf = 0; bf < 8; ++bf) {
        int n_row = wave_nn + bf * 16 + m16;
        bbase[bf] = n_row * 80 + hi8 * 2;
    }

    floatx4 acc[4][8];
#pragma unroll
    for (int mf = 0; mf < 4; ++mf)
#pragma unroll
        for (int bf = 0; bf < 8; ++bf) {
            floatx4 z = {0.f, 0.f, 0.f, 0.f};
            acc[mf][bf] = z;
        }

    const int srow = tid >> 2;   // 0..63
    const int scol = tid & 3;    // 0..3

    for (int k0 = 0; k0 < Kmax; k0 += 32) {
        __syncthreads();
        // stage B tile: Vt[n][k0..k0+31] -> ldsB[n][0..31] (row stride 40 halves)
#pragma unroll
        for (int rr = 0; rr < 4; ++rr) {
            int nn = srow + rr * 64;
            uint4 v = *reinterpret_cast<const uint4*>(Vt + (size_t)nn * 512 + k0 + scol * 8);
            *reinterpret_cast<uint4*>(reinterpret_cast<char*>(ldsB) + nn * 80 + scol * 16) = v;
        }
        __syncthreads();

        half8 a[4], b[8];
        const char* aptr = reinterpret_cast<const char*>(ldsA) + 2 * k0;
#pragma unroll
        for (int mf = 0; mf < 4; ++mf)
            a[mf] = *reinterpret_cast<const half8*>(aptr + abase[mf]);
        const char* bptr = reinterpret_cast<const char*>(ldsB);
#pragma unroll
        for (int bf = 0; bf < 8; ++bf)
            b[bf] = *reinterpret_cast<const half8*>(bptr + bbase[bf]);

#pragma unroll
        for (int mf = 0; mf < 4; ++mf)
#pragma unroll
            for (int bf = 0; bf < 8; ++bf)
                acc[mf][bf] = __builtin_amdgcn_mfma_f32_16x16x32_f16(
                    a[mf], b[bf], acc[mf][bf], 0, 0, 0);
    }

    // epilogue: C/D layout col=lane&15, row=quad*4+reg
#pragma unroll
    for (int mf = 0; mf < 4; ++mf) {
        int trow0 = t0 + wave_mt + mf * 16 + quad * 4;
#pragma unroll
        for (int bf = 0; bf < 8; ++bf) {
            int n = wave_nn + bf * 16 + m16;
#pragma unroll
            for (int reg = 0; reg < 4; ++reg) {
                int t = trow0 + reg;
                out[(size_t)t * 262144 + (size_t)bd * 256 + n] = acc[mf][bf][reg];
            }
        }
    }
}

// ---------------- launch ----------------

extern "C" void kernel_launch(void* const* d_in, const int* in_sizes, int n_in,
                              void* d_out, int out_size, void* d_ws, size_t ws_size,
                              hipStream_t stream) {
    const float* inputs = (const float*)d_in[0];   // (8,128,512)
    const float* A      = (const float*)d_in[1];   // (256,256)
    const float* Bvec   = (const float*)d_in[2];   // (256,)
    float* out = (float*)d_out;

    float* At   = (float*)d_ws;        // 65536 f
    float* A2   = At + 65536;
    float* A4   = A2 + 65536;
    float* A8   = A4 + 65536;
    float* A16  = A8 + 65536;
    float* A16t = A16 + 65536;
    float* U    = A16t + 65536;        // 8192 f
    _Float16* Vt = (_Float16*)(U + 8192);     // 256x512 halves
    _Float16* g8 = Vt + 131072;               // 1024 x 5248 halves

    k_at <<<256, 256, 0, stream>>>(A, At);
    k_g8 <<<1024, 256, 0, stream>>>(inputs, g8);
    k_sq <<<256, 256, 0, stream>>>(A,  A2,  A2,   0);
    k_sq <<<256, 256, 0, stream>>>(A2, A4,  A4,   0);
    k_sq <<<256, 256, 0, stream>>>(A4, A8,  A8,   0);
    k_sq <<<256, 256, 0, stream>>>(A8, A16, A16t, 1);
    k_u  <<<1, 256, 0, stream>>>(Bvec, A16t, U, Vt);
    k_v  <<<32, 256, 0, stream>>>(U, At, Vt);
    k_main<<<4096, 256, 0, stream>>>(g8, Vt, out);
}